// Round 9
// baseline (518.798 us; speedup 1.0000x reference)
//
#include <hip/hip_runtime.h>
#include <math.h>

#define D_   2048
#define E_   16
#define H_   1024
#define KSEL 4
#define B_   4096
#define CAP  4096

typedef short bf16x8_t __attribute__((ext_vector_type(8)));
typedef float f32x4_t  __attribute__((ext_vector_type(4)));

__device__ __forceinline__ unsigned short f2bf(float f) {
  unsigned u = __float_as_uint(f);
  u += 0x7FFFu + ((u >> 16) & 1u);   // RNE
  return (unsigned short)(u >> 16);
}

__device__ __forceinline__ float bf2f(unsigned short h) {
  unsigned u = (unsigned)h << 16;
  return __uint_as_float(u);
}

__device__ __forceinline__ void gld16(const void* g, void* l) {
  __builtin_amdgcn_global_load_lds(
      (const __attribute__((address_space(1))) unsigned int*)g,
      (__attribute__((address_space(3))) unsigned int*)l, 16, 0, 0);
}

// ---------------- x -> bf16 ----------------
__global__ void k_prep(const float* __restrict__ x, unsigned short* __restrict__ xb) {
  int i = blockIdx.x * 256 + threadIdx.x;          // one float4 per thread
  float4 v = ((const float4*)x)[i];
  ushort4 o;
  o.x = f2bf(v.x); o.y = f2bf(v.y); o.z = f2bf(v.z); o.w = f2bf(v.w);
  ((ushort4*)xb)[i] = o;
}

// ---------------- W [E][R][C] f32 -> Wt [E][C][R] bf16 ----------------
__global__ void k_transw(const float* __restrict__ in, unsigned short* __restrict__ out,
                         int R, int C) {
  __shared__ float tile[32][33];
  size_t ebase = (size_t)blockIdx.z * R * C;
  in += ebase; out += ebase;
  int c0 = blockIdx.x * 32, r0 = blockIdx.y * 32;
  int tx = threadIdx.x & 31, ty = threadIdx.x >> 5;
#pragma unroll
  for (int i = ty; i < 32; i += 8)
    tile[i][tx] = in[(size_t)(r0 + i) * C + c0 + tx];
  __syncthreads();
  // write ushort2 pairs along R (output-contiguous)
#pragma unroll
  for (int w = threadIdx.x; w < 32 * 16; w += 256) {
    int i = w >> 4, rp = w & 15;
    ushort2 v;
    v.x = f2bf(tile[2 * rp][i]);
    v.y = f2bf(tile[2 * rp + 1][i]);
    *(ushort2*)(out + (size_t)(c0 + i) * R + r0 + 2 * rp) = v;
  }
}

// ---------------- Wr [D][E] f32 -> WrT [E][D] f32 (128 KB, one-shot) ----------
__global__ void k_transr(const float* __restrict__ in, float* __restrict__ out) {
  int i = blockIdx.x * 256 + threadIdx.x;   // coalesced read over D*E
  int d = i >> 4, e = i & 15;
  out[e * D_ + d] = in[i];                  // scattered 16-stream write; L2 absorbs
}

// ---------------- router: logits, top-4, softmax -> tops/topw (NO atomics) ----
__global__ __launch_bounds__(256) void k_router(
    const float* __restrict__ x, const float* __restrict__ wrT, const float* __restrict__ br,
    int* __restrict__ tops, float* __restrict__ topw) {
  int wid = threadIdx.x >> 6, lane = threadIdx.x & 63;
  int t = blockIdx.x * 4 + wid;
  float acc[E_];
#pragma unroll
  for (int e = 0; e < E_; e++) acc[e] = 0.f;
  const float4* xr = (const float4*)(x + (size_t)t * D_);
#pragma unroll
  for (int j = 0; j < D_ / 256; j++) {
    float4 xv = xr[j * 64 + lane];
#pragma unroll
    for (int e = 0; e < E_; e++) {
      float4 wv = ((const float4*)(wrT + (size_t)e * D_))[j * 64 + lane];
      acc[e] += xv.x * wv.x + xv.y * wv.y + xv.z * wv.z + xv.w * wv.w;
    }
  }
#pragma unroll
  for (int e = 0; e < E_; e++) {
    float v = acc[e];
    for (int m = 32; m >= 1; m >>= 1) v += __shfl_xor(v, m);
    acc[e] = v;
  }
  if (lane == 0) {
    float lg[E_];
#pragma unroll
    for (int e = 0; e < E_; e++) lg[e] = acc[e] + br[e];
    unsigned used = 0; int sel[KSEL]; float sv[KSEL];
    for (int k = 0; k < KSEL; k++) {
      float best = -1e30f; int bi = 0;
      for (int e = 0; e < E_; e++)
        if (!((used >> e) & 1u) && lg[e] > best) { best = lg[e]; bi = e; }
      used |= 1u << bi; sel[k] = bi; sv[k] = best;
    }
    float mx = sv[0], s = 0.f, w[KSEL];
    for (int k = 0; k < KSEL; k++) { w[k] = expf(sv[k] - mx); s += w[k]; }
    float inv = 1.f / s;
    int4 ti; float4 tw;
    ti.x = sel[0]; ti.y = sel[1]; ti.z = sel[2]; ti.w = sel[3];
    tw.x = w[0] * inv; tw.y = w[1] * inv; tw.z = w[2] * inv; tw.w = w[3] * inv;
    ((int4*)tops)[t] = ti;
    ((float4*)topw)[t] = tw;
  }
}

// ------- build per-expert token lists + inverse map (deterministic, no atomics)
__global__ __launch_bounds__(256) void k_build(
    const int* __restrict__ tops, const float* __restrict__ topw,
    int* __restrict__ counts, int* __restrict__ ids, float* __restrict__ wts,
    int* __restrict__ inv) {
  int e = blockIdx.x;
  int tid = threadIdx.x, lane = tid & 63, wid = tid >> 6;
  __shared__ int wsum[4];
  __shared__ int red[4];
  int base = 0;
  int pre = 0;                               // picks with expert < e (per thread)
  for (int c = 0; c < B_; c += 256) {
    int t = c + tid;
    int4 tk = ((const int4*)tops)[t];
    pre += (tk.x < e) + (tk.y < e) + (tk.z < e) + (tk.w < e);
    int k = -1;
    if (tk.x == e) k = 0; else if (tk.y == e) k = 1;
    else if (tk.z == e) k = 2; else if (tk.w == e) k = 3;
    unsigned long long mask = __ballot(k >= 0);
    int myoff = __popcll(mask & ((1ull << lane) - 1ull));
    if (lane == 0) wsum[wid] = __popcll(mask);
    __syncthreads();
    int woff = 0;
#pragma unroll
    for (int i = 0; i < 4; i++) if (i < wid) woff += wsum[i];
    int ctotal = wsum[0] + wsum[1] + wsum[2] + wsum[3];
    if (k >= 0) {
      int slot = base + woff + myoff;
      ids[e * CAP + slot] = t;
      wts[e * CAP + slot] = topw[t * 4 + k];
    }
    base += ctotal;
    __syncthreads();
  }
  if (tid == 0) counts[e] = base;
  for (int m = 32; m >= 1; m >>= 1) pre += __shfl_xor(pre, m);
  if (lane == 0) red[wid] = pre;
  __syncthreads();
  int offe = red[0] + red[1] + red[2] + red[3];
  for (int s = tid; s < base; s += 256) {
    int t = ids[e * CAP + s];
    int4 tk = ((const int4*)tops)[t];
    int k = (tk.x == e) ? 0 : (tk.y == e) ? 1 : (tk.z == e) ? 2 : 3;
    inv[t * 4 + k] = offe + s;
  }
}

// ---------------- gather: out[t] = x[t] + sum_k ybuf[inv[t][k]] ----------------
__global__ __launch_bounds__(256) void k_gather(
    const float* __restrict__ x, const unsigned short* __restrict__ ybuf,
    const int* __restrict__ inv, float* __restrict__ out) {
  int t = blockIdx.x;
  int4 iv = ((const int4*)inv)[t];
  const ushort4* y0 = (const ushort4*)(ybuf + (size_t)iv.x * D_);
  const ushort4* y1 = (const ushort4*)(ybuf + (size_t)iv.y * D_);
  const ushort4* y2 = (const ushort4*)(ybuf + (size_t)iv.z * D_);
  const ushort4* y3 = (const ushort4*)(ybuf + (size_t)iv.w * D_);
  const float4* xr = (const float4*)(x + (size_t)t * D_);
  float4* orow = (float4*)(out + (size_t)t * D_);
#pragma unroll
  for (int i = threadIdx.x; i < D_ / 4; i += 256) {
    float4 v = xr[i];
    ushort4 a = y0[i], b = y1[i], c = y2[i], d = y3[i];
    v.x += bf2f(a.x) + bf2f(b.x) + bf2f(c.x) + bf2f(d.x);
    v.y += bf2f(a.y) + bf2f(b.y) + bf2f(c.y) + bf2f(d.y);
    v.z += bf2f(a.z) + bf2f(b.z) + bf2f(c.z) + bf2f(d.z);
    v.w += bf2f(a.w) + bf2f(b.w) + bf2f(c.w) + bf2f(d.w);
    orow[i] = v;
  }
}

// ====== GEMM geometry: BM=128 x BN=256, BK=64, 8 waves (512 thr) ======
// wave (wm,wn) of 2x4 owns 64x64: af[4], bfr[4], acc[4][4] (64 AGPR).
// LDS: TRIPLE buffer (A 16KB + B 32KB per buf = 144 KB), 1 block/CU.
// Counted-vmcnt pipeline (T3/T4): at iter kt issue stage(kt+2) [6 gld16/thr],
// compute buf[kt], then vmcnt(6) (waits ONLY buf[kt+1]'s loads; 6 newest stay
// in flight) + raw s_barrier. No full vmcnt(0) drain inside the loop.
#define GSTAGE(ASb, BSb, ktt) do {                                   \
    int ko_ = (ktt) * 64;                                            \
    _Pragma("unroll")                                                \
    for (int i_ = 0; i_ < 2; i_++)                                   \
      gld16(a_src[i_] + ko_, (ASb) + (wid * 2 + i_) * 512);          \
    _Pragma("unroll")                                                \
    for (int j_ = 0; j_ < 4; j_++)                                   \
      gld16(b_src[j_] + ko_, (BSb) + (wid * 4 + j_) * 512);          \
  } while (0)

#define GCOMPUTE(ASb, BSb) do {                                      \
    __builtin_amdgcn_s_setprio(1);                                   \
    _Pragma("unroll")                                                \
    for (int kb = 0; kb < 2; kb++) {                                 \
      bf16x8_t af[4], bfr[4];                                        \
      _Pragma("unroll")                                              \
      for (int m = 0; m < 4; m++) {                                  \
        int row = wm * 64 + m * 16 + (lane & 15);                    \
        int ss = (kb * 4 + (lane >> 4)) ^ (row & 7);                 \
        af[m] = *(const bf16x8_t*)((ASb) + row * 64 + ss * 8);       \
      }                                                              \
      _Pragma("unroll")                                              \
      for (int n = 0; n < 4; n++) {                                  \
        int row = wn * 64 + n * 16 + (lane & 15);                    \
        int ss = (kb * 4 + (lane >> 4)) ^ (row & 7);                 \
        bfr[n] = *(const bf16x8_t*)((BSb) + row * 64 + ss * 8);      \
      }                                                              \
      _Pragma("unroll")                                              \
      for (int m = 0; m < 4; m++)                                    \
        _Pragma("unroll")                                            \
        for (int n = 0; n < 4; n++)                                  \
          acc[m][n] = __builtin_amdgcn_mfma_f32_16x16x32_bf16(       \
              af[m], bfr[n], acc[m][n], 0, 0, 0);                    \
    }                                                                \
    __builtin_amdgcn_s_setprio(0);                                   \
  } while (0)

#define GBAR_COUNTED(cond) do {                                      \
    if (cond) asm volatile("s_waitcnt vmcnt(6)" ::: "memory");       \
    else      asm volatile("s_waitcnt vmcnt(0)" ::: "memory");       \
    __builtin_amdgcn_sched_barrier(0);                               \
    __builtin_amdgcn_s_barrier();                                    \
    __builtin_amdgcn_sched_barrier(0);                               \
  } while (0)

// ---------------- GEMM1: h = relu(X[ids] @ W1t^T + b1), bf16 out ----------------
__global__ __launch_bounds__(512, 2) void k_gemm1(
    const unsigned short* __restrict__ xb,   // [B][D] bf16
    const unsigned short* __restrict__ w1t,  // [E][H][D] bf16
    const float* __restrict__ b1,            // [E][H]
    const int* __restrict__ ids, const int* __restrict__ counts,
    unsigned short* __restrict__ hbuf)       // [sum cnt][H] bf16
{
  __shared__ unsigned short As[3][128 * 64];
  __shared__ unsigned short Bs[3][256 * 64];
  const int NKT = D_ / 64;                   // 32
  int cnts[E_], offsv[E_], rowt[E_];
  int s = 0, ntr = 0;
#pragma unroll
  for (int e = 0; e < E_; e++) {
    cnts[e] = counts[e];
    offsv[e] = s; s += cnts[e];
    rowt[e] = (cnts[e] + 127) >> 7; ntr += rowt[e];
  }
  const int NS = H_ / 256;                   // 4 col slabs
  int totalTiles = ntr * NS;
  int tid = threadIdx.x, lane = tid & 63, wid = tid >> 6;   // wid 0..7
  int wm = wid >> 2, wn = wid & 3;
  int cr = lane >> 3, slot = lane & 7;
  int sw = (slot ^ cr) << 3;
  int hi = lane >> 4, cl = lane & 15;
  int bswz = (blockIdx.x & 7) * (gridDim.x >> 3) + (blockIdx.x >> 3);

  for (int tile = bswz; tile < totalTiles; tile += gridDim.x) {
    int slab = tile / ntr;                   // slab-outer, row-inner
    int rtg = tile - slab * ntr;
    int n0 = slab << 8;
    int e = 0, base = 0;
    while (e < E_ - 1 && rtg >= base + rowt[e]) { base += rowt[e]; e++; }
    int rt = rtg - base;
    int cnt = cnts[e];
    int r0 = rt << 7;

    const unsigned short* a_src[2];
    const unsigned short* b_src[4];
    const unsigned short* wbase = w1t + (size_t)e * H_ * D_;
#pragma unroll
    for (int i = 0; i < 2; i++) {
      int chunk = wid * 2 + i;               // 16 chunks x 8 rows = 128
      int rr = r0 + chunk * 8 + cr;
      int rc = min(rr, cnt - 1);
      int tok = ids[e * CAP + rc];
      a_src[i] = xb + (size_t)tok * D_ + sw;
    }
#pragma unroll
    for (int j = 0; j < 4; j++) {
      int chunk = wid * 4 + j;               // 32 chunks x 8 rows = 256
      b_src[j] = wbase + (size_t)(n0 + chunk * 8 + cr) * D_ + sw;
    }
    f32x4_t acc[4][4];
#pragma unroll
    for (int m = 0; m < 4; m++)
#pragma unroll
      for (int n = 0; n < 4; n++) acc[m][n] = (f32x4_t){0.f, 0.f, 0.f, 0.f};

    // prologue: stage kt=0,1
    GSTAGE(As[0], Bs[0], 0);
    GSTAGE(As[1], Bs[1], 1);
    asm volatile("s_waitcnt vmcnt(6)" ::: "memory");   // buf0 ready
    __builtin_amdgcn_sched_barrier(0);
    __builtin_amdgcn_s_barrier();
    __builtin_amdgcn_sched_barrier(0);
    for (int kt = 0; kt < NKT; kt++) {
      int cur = kt % 3;
      if (kt + 2 < NKT) {
        int nb = (kt + 2) % 3;
        GSTAGE(As[nb], Bs[nb], kt + 2);
      }
      GCOMPUTE(As[cur], Bs[cur]);
      GBAR_COUNTED(kt + 2 < NKT);
    }
    int offe = offsv[e];
    float bias[4];
#pragma unroll
    for (int n = 0; n < 4; n++)
      bias[n] = b1[e * H_ + n0 + wn * 64 + n * 16 + cl];
#pragma unroll
    for (int m = 0; m < 4; m++)
#pragma unroll
      for (int j = 0; j < 4; j++) {
        int sr = r0 + wm * 64 + m * 16 + hi * 4 + j;
        if (sr < cnt) {
          size_t rowb = (size_t)(offe + sr) * H_;
#pragma unroll
          for (int n = 0; n < 4; n++) {
            int col = n0 + wn * 64 + n * 16 + cl;
            float v = acc[m][n][j] + bias[n];
            v = v > 0.f ? v : 0.f;
            hbuf[rowb + col] = f2bf(v);
          }
        }
      }
  }
}

// ------ GEMM2: ybuf[gslot] = w * (h @ W2t^T + b2)  (bf16 streaming stores) ------
__global__ __launch_bounds__(512, 2) void k_gemm2(
    const unsigned short* __restrict__ hbuf, // [sum cnt][H] bf16
    const unsigned short* __restrict__ w2t,  // [E][D][H] bf16
    const float* __restrict__ b2,            // [E][D]
    const float* __restrict__ wts,
    const int* __restrict__ counts,
    unsigned short* __restrict__ ybuf)       // [sum cnt][D] bf16
{
  __shared__ unsigned short As[3][128 * 64];
  __shared__ unsigned short Bs[3][256 * 64];
  const int NKT = H_ / 64;                   // 16
  int cnts[E_], offsv[E_], rowt[E_];
  int s = 0, ntr = 0;
#pragma unroll
  for (int e = 0; e < E_; e++) {
    cnts[e] = counts[e];
    offsv[e] = s; s += cnts[e];
    rowt[e] = (cnts[e] + 127) >> 7; ntr += rowt[e];
  }
  const int NS = D_ / 256;                   // 8 col slabs
  int totalTiles = ntr * NS;
  int tid = threadIdx.x, lane = tid & 63, wid = tid >> 6;
  int wm = wid >> 2, wn = wid & 3;
  int cr = lane >> 3, slot = lane & 7;
  int sw = (slot ^ cr) << 3;
  int hi = lane >> 4, cl = lane & 15;
  int bswz = (blockIdx.x & 7) * (gridDim.x >> 3) + (blockIdx.x >> 3);

  for (int tile = bswz; tile < totalTiles; tile += gridDim.x) {
    int slab = tile / ntr;
    int rtg = tile - slab * ntr;
    int n0 = slab << 8;
    int e = 0, base = 0;
    while (e < E_ - 1 && rtg >= base + rowt[e]) { base += rowt[e]; e++; }
    int rt = rtg - base;
    int cnt = cnts[e];
    int r0 = rt << 7;
    int offe = offsv[e];

    const unsigned short* a_src[2];
    const unsigned short* b_src[4];
    const unsigned short* wbase = w2t + (size_t)e * D_ * H_;
#pragma unroll
    for (int i = 0; i < 2; i++) {
      int chunk = wid * 2 + i;
      int rr = r0 + chunk * 8 + cr;
      int rc = min(rr, cnt - 1);
      a_src[i] = hbuf + (size_t)(offe + rc) * H_ + sw;
    }
#pragma unroll
    for (int j = 0; j < 4; j++) {
      int chunk = wid * 4 + j;
      b_src[j] = wbase + (size_t)(n0 + chunk * 8 + cr) * H_ + sw;
    }
    f32x4_t acc[4][4];
#pragma unroll
    for (int m = 0; m < 4; m++)
#pragma unroll
      for (int n = 0; n < 4; n++) acc[m][n] = (f32x4_t){0.f, 0.f, 0.f, 0.f};

    GSTAGE(As[0], Bs[0], 0);
    GSTAGE(As[1], Bs[1], 1);
    asm volatile("s_waitcnt vmcnt(6)" ::: "memory");
    __builtin_amdgcn_sched_barrier(0);
    __builtin_amdgcn_s_barrier();
    __builtin_amdgcn_sched_barrier(0);
    for (int kt = 0; kt < NKT; kt++) {
      int cur = kt % 3;
      if (kt + 2 < NKT) {
        int nb = (kt + 2) % 3;
        GSTAGE(As[nb], Bs[nb], kt + 2);
      }
      GCOMPUTE(As[cur], Bs[cur]);
      GBAR_COUNTED(kt + 2 < NKT);
    }
    float bias[4];
#pragma unroll
    for (int n = 0; n < 4; n++)
      bias[n] = b2[e * D_ + n0 + wn * 64 + n * 16 + cl];
#pragma unroll
    for (int m = 0; m < 4; m++)
#pragma unroll
      for (int j = 0; j < 4; j++) {
        int sr = r0 + wm * 64 + m * 16 + hi * 4 + j;
        if (sr < cnt) {
          float w = wts[e * CAP + sr];
          unsigned short* yrow = ybuf + (size_t)(offe + sr) * D_;
#pragma unroll
          for (int n = 0; n < 4; n++) {
            int col = n0 + wn * 64 + n * 16 + cl;
            yrow[col] = f2bf(w * (acc[m][n][j] + bias[n]));
          }
        }
      }
  }
}

extern "C" void kernel_launch(void* const* d_in, const int* in_sizes, int n_in,
                              void* d_out, int out_size, void* d_ws, size_t ws_size,
                              hipStream_t stream) {
  const float* x  = (const float*)d_in[0];
  const float* W1 = (const float*)d_in[1];
  const float* b1 = (const float*)d_in[2];
  const float* W2 = (const float*)d_in[3];
  const float* b2 = (const float*)d_in[4];
  const float* Wr = (const float*)d_in[5];
  const float* br = (const float*)d_in[6];
  float* out = (float*)d_out;
  char* ws = (char*)d_ws;
  // workspace layout (~176.9 MiB total). ybuf ALIASES W1t (dead after gemm1).
  unsigned short* W1t  = (unsigned short*)(ws);                // 67108864 B [E][H][D] bf16
  unsigned short* ybuf = (unsigned short*)(ws);                // 67108864 B [16384][D] bf16
  unsigned short* W2t  = (unsigned short*)(ws + 67108864);     // 67108864 B [E][D][H] bf16
  unsigned short* xb   = (unsigned short*)(ws + 134217728);    // 16777216 B [B][D] bf16
  unsigned short* hb   = (unsigned short*)(ws + 150994944);    // 33554432 B [B*K][H] bf16
  int*   ids    = (int*)  (ws + 184549376);                    // 262144 B
  float* wts    = (float*)(ws + 184811520);                    // 262144 B
  int*   counts = (int*)  (ws + 185073664);                    // 64 B
  float* wrT    = (float*)(ws + 185073728);                    // 131072 B [E][D] f32
  int*   tops   = (int*)  (ws + 185204800);                    // 65536 B [B][4]
  float* topw   = (float*)(ws + 185270336);                    // 65536 B [B][4]
  int*   inv    = (int*)  (ws + 185335872);                    // 65536 B [B][4]

  k_prep<<<8192, 256, 0, stream>>>(x, xb);
  k_transr<<<128, 256, 0, stream>>>(Wr, wrT);
  k_transw<<<dim3(32, 64, 16), 256, 0, stream>>>(W1, W1t, 2048, 1024);
  k_transw<<<dim3(64, 32, 16), 256, 0, stream>>>(W2, W2t, 1024, 2048);
  k_router<<<1024, 256, 0, stream>>>(x, wrT, br, tops, topw);
  k_build<<<16, 256, 0, stream>>>(tops, topw, counts, ids, wts, inv);
  k_gemm1<<<256, 512, 0, stream>>>(xb, W1t, b1, ids, counts, hb);
  k_gemm2<<<256, 512, 0, stream>>>(hb, W2t, b2, wts, counts, ybuf);
  k_gather<<<4096, 256, 0, stream>>>(x, ybuf, inv, out);
}

// Round 10
// 501.031 us; speedup vs baseline: 1.0355x; 1.0355x over previous
//
#include <hip/hip_runtime.h>
#include <math.h>

#define D_   2048
#define E_   16
#define H_   1024
#define KSEL 4
#define B_   4096
#define CAP  4096

typedef short bf16x8_t __attribute__((ext_vector_type(8)));
typedef float f32x4_t  __attribute__((ext_vector_type(4)));

__device__ __forceinline__ unsigned short f2bf(float f) {
  unsigned u = __float_as_uint(f);
  u += 0x7FFFu + ((u >> 16) & 1u);   // RNE
  return (unsigned short)(u >> 16);
}

__device__ __forceinline__ float bf2f(unsigned short h) {
  unsigned u = (unsigned)h << 16;
  return __uint_as_float(u);
}

__device__ __forceinline__ void gld16(const void* g, void* l) {
  __builtin_amdgcn_global_load_lds(
      (const __attribute__((address_space(1))) unsigned int*)g,
      (__attribute__((address_space(3))) unsigned int*)l, 16, 0, 0);
}

// ---------------- W [E][R][C] f32 -> Wt [E][C][R] bf16 ----------------
__global__ void k_transw(const float* __restrict__ in, unsigned short* __restrict__ out,
                         int R, int C) {
  __shared__ float tile[32][33];
  size_t ebase = (size_t)blockIdx.z * R * C;
  in += ebase; out += ebase;
  int c0 = blockIdx.x * 32, r0 = blockIdx.y * 32;
  int tx = threadIdx.x & 31, ty = threadIdx.x >> 5;
#pragma unroll
  for (int i = ty; i < 32; i += 8)
    tile[i][tx] = in[(size_t)(r0 + i) * C + c0 + tx];
  __syncthreads();
  // write ushort2 pairs along R (output-contiguous)
#pragma unroll
  for (int w = threadIdx.x; w < 32 * 16; w += 256) {
    int i = w >> 4, rp = w & 15;
    ushort2 v;
    v.x = f2bf(tile[2 * rp][i]);
    v.y = f2bf(tile[2 * rp + 1][i]);
    *(ushort2*)(out + (size_t)(c0 + i) * R + r0 + 2 * rp) = v;
  }
}

// ---------------- Wr [D][E] f32 -> WrT [E][D] f32 (128 KB, one-shot) ----------
__global__ void k_transr(const float* __restrict__ in, float* __restrict__ out) {
  int i = blockIdx.x * 256 + threadIdx.x;   // coalesced read over D*E
  int d = i >> 4, e = i & 15;
  out[e * D_ + d] = in[i];                  // scattered 16-stream write; L2 absorbs
}

// ------- fused: router (logits/top4/softmax -> tops/topw) + x->bf16 store ------
// 1 wave per token; x row read ONCE for both logits and xb conversion.
__global__ __launch_bounds__(256) void k_router(
    const float* __restrict__ x, const float* __restrict__ wrT, const float* __restrict__ br,
    unsigned short* __restrict__ xb, int* __restrict__ tops, float* __restrict__ topw) {
  int wid = threadIdx.x >> 6, lane = threadIdx.x & 63;
  int t = blockIdx.x * 4 + wid;
  float acc[E_];
#pragma unroll
  for (int e = 0; e < E_; e++) acc[e] = 0.f;
  const float4* xr = (const float4*)(x + (size_t)t * D_);
  ushort4* xbw = (ushort4*)(xb + (size_t)t * D_);
#pragma unroll
  for (int j = 0; j < D_ / 256; j++) {
    float4 xv = xr[j * 64 + lane];
    ushort4 o;
    o.x = f2bf(xv.x); o.y = f2bf(xv.y); o.z = f2bf(xv.z); o.w = f2bf(xv.w);
    xbw[j * 64 + lane] = o;
#pragma unroll
    for (int e = 0; e < E_; e++) {
      float4 wv = ((const float4*)(wrT + (size_t)e * D_))[j * 64 + lane];
      acc[e] += xv.x * wv.x + xv.y * wv.y + xv.z * wv.z + xv.w * wv.w;
    }
  }
#pragma unroll
  for (int e = 0; e < E_; e++) {
    float v = acc[e];
    for (int m = 32; m >= 1; m >>= 1) v += __shfl_xor(v, m);
    acc[e] = v;
  }
  if (lane == 0) {
    float lg[E_];
#pragma unroll
    for (int e = 0; e < E_; e++) lg[e] = acc[e] + br[e];
    unsigned used = 0; int sel[KSEL]; float sv[KSEL];
    for (int k = 0; k < KSEL; k++) {
      float best = -1e30f; int bi = 0;
      for (int e = 0; e < E_; e++)
        if (!((used >> e) & 1u) && lg[e] > best) { best = lg[e]; bi = e; }
      used |= 1u << bi; sel[k] = bi; sv[k] = best;
    }
    float mx = sv[0], s = 0.f, w[KSEL];
    for (int k = 0; k < KSEL; k++) { w[k] = expf(sv[k] - mx); s += w[k]; }
    float inv = 1.f / s;
    int4 ti; float4 tw;
    ti.x = sel[0]; ti.y = sel[1]; ti.z = sel[2]; ti.w = sel[3];
    tw.x = w[0] * inv; tw.y = w[1] * inv; tw.z = w[2] * inv; tw.w = w[3] * inv;
    ((int4*)tops)[t] = ti;
    ((float4*)topw)[t] = tw;
  }
}

// ------- build per-expert token lists + inverse map (deterministic, no atomics)
__global__ __launch_bounds__(256) void k_build(
    const int* __restrict__ tops, const float* __restrict__ topw,
    int* __restrict__ counts, int* __restrict__ ids, float* __restrict__ wts,
    int* __restrict__ inv) {
  int e = blockIdx.x;
  int tid = threadIdx.x, lane = tid & 63, wid = tid >> 6;
  __shared__ int wsum[4];
  __shared__ int red[4];
  int base = 0;
  int pre = 0;                               // picks with expert < e (per thread)
  for (int c = 0; c < B_; c += 256) {
    int t = c + tid;
    int4 tk = ((const int4*)tops)[t];
    pre += (tk.x < e) + (tk.y < e) + (tk.z < e) + (tk.w < e);
    int k = -1;
    if (tk.x == e) k = 0; else if (tk.y == e) k = 1;
    else if (tk.z == e) k = 2; else if (tk.w == e) k = 3;
    unsigned long long mask = __ballot(k >= 0);
    int myoff = __popcll(mask & ((1ull << lane) - 1ull));
    if (lane == 0) wsum[wid] = __popcll(mask);
    __syncthreads();
    int woff = 0;
#pragma unroll
    for (int i = 0; i < 4; i++) if (i < wid) woff += wsum[i];
    int ctotal = wsum[0] + wsum[1] + wsum[2] + wsum[3];
    if (k >= 0) {
      int slot = base + woff + myoff;
      ids[e * CAP + slot] = t;
      wts[e * CAP + slot] = topw[t * 4 + k];
    }
    base += ctotal;
    __syncthreads();
  }
  if (tid == 0) counts[e] = base;
  for (int m = 32; m >= 1; m >>= 1) pre += __shfl_xor(pre, m);
  if (lane == 0) red[wid] = pre;
  __syncthreads();
  int offe = red[0] + red[1] + red[2] + red[3];
  for (int s = tid; s < base; s += 256) {
    int t = ids[e * CAP + s];
    int4 tk = ((const int4*)tops)[t];
    int k = (tk.x == e) ? 0 : (tk.y == e) ? 1 : (tk.z == e) ? 2 : 3;
    inv[t * 4 + k] = offe + s;
  }
}

// ---------------- gather: out[t] = x[t] + sum_k ybuf[inv[t][k]] ----------------
__global__ __launch_bounds__(256) void k_gather(
    const float* __restrict__ x, const unsigned short* __restrict__ ybuf,
    const int* __restrict__ inv, float* __restrict__ out) {
  int t = blockIdx.x;
  int4 iv = ((const int4*)inv)[t];
  const ushort4* y0 = (const ushort4*)(ybuf + (size_t)iv.x * D_);
  const ushort4* y1 = (const ushort4*)(ybuf + (size_t)iv.y * D_);
  const ushort4* y2 = (const ushort4*)(ybuf + (size_t)iv.z * D_);
  const ushort4* y3 = (const ushort4*)(ybuf + (size_t)iv.w * D_);
  const float4* xr = (const float4*)(x + (size_t)t * D_);
  float4* orow = (float4*)(out + (size_t)t * D_);
#pragma unroll
  for (int i = threadIdx.x; i < D_ / 4; i += 256) {
    float4 v = xr[i];
    ushort4 a = y0[i], b = y1[i], c = y2[i], d = y3[i];
    v.x += bf2f(a.x) + bf2f(b.x) + bf2f(c.x) + bf2f(d.x);
    v.y += bf2f(a.y) + bf2f(b.y) + bf2f(c.y) + bf2f(d.y);
    v.z += bf2f(a.z) + bf2f(b.z) + bf2f(c.z) + bf2f(d.z);
    v.w += bf2f(a.w) + bf2f(b.w) + bf2f(c.w) + bf2f(d.w);
    orow[i] = v;
  }
}

// ====== GEMM geometry: BM=256 x BN=256, BK=64, 8 waves (512 thr) ======
// 2x arithmetic intensity vs 128-row tiles (staging-BW was the R6/R8 limiter).
// wave (wm,wn) of 2x4 owns 128x64: af[8], bfr[4], acc[8][4] (128 AGPR).
// LDS 128KB: As[2]/Bs[2] 32KB each, 2-phase dbuf (R7 structure, race-tested):
//   stage(next) -> ds_read+MFMA(cur) -> __syncthreads() -> swap.
// XOR-swizzled staging (pre-swizzled global source, linear LDS dest).

// ---------------- GEMM1: h = relu(X[ids] @ W1t^T + b1), bf16 out ----------------
__global__ __launch_bounds__(512, 2) void k_gemm1(
    const unsigned short* __restrict__ xb,   // [B][D] bf16
    const unsigned short* __restrict__ w1t,  // [E][H][D] bf16
    const float* __restrict__ b1,            // [E][H]
    const int* __restrict__ ids, const int* __restrict__ counts,
    unsigned short* __restrict__ hbuf)       // [sum cnt][H] bf16
{
  __shared__ unsigned short As[2][256 * 64];
  __shared__ unsigned short Bs[2][256 * 64];
  int cnts[E_], offsv[E_], rowt[E_];
  int s = 0, ntr = 0;
#pragma unroll
  for (int e = 0; e < E_; e++) {
    cnts[e] = counts[e];
    offsv[e] = s; s += cnts[e];
    rowt[e] = (cnts[e] + 255) >> 8; ntr += rowt[e];
  }
  const int NS = H_ / 256;                   // 4 col slabs
  int totalTiles = ntr * NS;
  int tid = threadIdx.x, lane = tid & 63, wid = tid >> 6;   // wid 0..7
  int wm = wid >> 2, wn = wid & 3;
  int cr = lane >> 3, slot = lane & 7;
  int sw = (slot ^ cr) << 3;                 // pre-swizzled k-chunk (elements)
  int hi = lane >> 4, cl = lane & 15;
  int bswz = (blockIdx.x & 7) * (gridDim.x >> 3) + (blockIdx.x >> 3);

  for (int tile = bswz; tile < totalTiles; tile += gridDim.x) {
    int slab = tile / ntr;                   // slab-outer, row-inner
    int rtg = tile - slab * ntr;
    int n0 = slab << 8;
    int e = 0, base = 0;
    while (e < E_ - 1 && rtg >= base + rowt[e]) { base += rowt[e]; e++; }
    int rt = rtg - base;
    int cnt = cnts[e];
    int r0 = rt << 8;

    const unsigned short* a_src[4];
    const unsigned short* b_src[4];
    const unsigned short* wbase = w1t + (size_t)e * H_ * D_;
#pragma unroll
    for (int i = 0; i < 4; i++) {
      int chunk = wid * 4 + i;               // 32 chunks x 8 rows = 256
      int rr = r0 + chunk * 8 + cr;
      int rc = min(rr, cnt - 1);
      int tok = ids[e * CAP + rc];
      a_src[i] = xb + (size_t)tok * D_ + sw;
      b_src[i] = wbase + (size_t)(n0 + chunk * 8 + cr) * D_ + sw;
    }
    f32x4_t acc[8][4];
#pragma unroll
    for (int m = 0; m < 8; m++)
#pragma unroll
      for (int n = 0; n < 4; n++) acc[m][n] = (f32x4_t){0.f, 0.f, 0.f, 0.f};

    // prologue: stage k-step 0
#pragma unroll
    for (int i = 0; i < 4; i++) {
      gld16(a_src[i], As[0] + (wid * 4 + i) * 512);
      gld16(b_src[i], Bs[0] + (wid * 4 + i) * 512);
    }
    __syncthreads();
    int cur = 0;
    for (int kt = 0; kt < D_ / 64; kt++) {
      if (kt + 1 < D_ / 64) {                // issue next-tile loads FIRST
        int ko = (kt + 1) * 64;
#pragma unroll
        for (int i = 0; i < 4; i++) {
          gld16(a_src[i] + ko, As[cur ^ 1] + (wid * 4 + i) * 512);
          gld16(b_src[i] + ko, Bs[cur ^ 1] + (wid * 4 + i) * 512);
        }
      }
#pragma unroll
      for (int kb = 0; kb < 2; kb++) {
        bf16x8_t af[8], bfr[4];
#pragma unroll
        for (int m = 0; m < 8; m++) {
          int row = wm * 128 + m * 16 + (lane & 15);
          int ss = (kb * 4 + (lane >> 4)) ^ (row & 7);
          af[m] = *(const bf16x8_t*)(As[cur] + row * 64 + ss * 8);
        }
#pragma unroll
        for (int n = 0; n < 4; n++) {
          int row = wn * 64 + n * 16 + (lane & 15);
          int ss = (kb * 4 + (lane >> 4)) ^ (row & 7);
          bfr[n] = *(const bf16x8_t*)(Bs[cur] + row * 64 + ss * 8);
        }
#pragma unroll
        for (int m = 0; m < 8; m++)
#pragma unroll
          for (int n = 0; n < 4; n++)
            acc[m][n] = __builtin_amdgcn_mfma_f32_16x16x32_bf16(af[m], bfr[n], acc[m][n], 0, 0, 0);
      }
      __syncthreads();                       // prefetch flew during MFMA
      cur ^= 1;
    }
    int offe = offsv[e];
    float bias[4];
#pragma unroll
    for (int n = 0; n < 4; n++)
      bias[n] = b1[e * H_ + n0 + wn * 64 + n * 16 + cl];
#pragma unroll
    for (int m = 0; m < 8; m++)
#pragma unroll
      for (int j = 0; j < 4; j++) {
        int sr = r0 + wm * 128 + m * 16 + hi * 4 + j;
        if (sr < cnt) {
          size_t rowb = (size_t)(offe + sr) * H_;
#pragma unroll
          for (int n = 0; n < 4; n++) {
            int col = n0 + wn * 64 + n * 16 + cl;
            float v = acc[m][n][j] + bias[n];
            v = v > 0.f ? v : 0.f;
            hbuf[rowb + col] = f2bf(v);
          }
        }
      }
  }
}

// ------ GEMM2: ybuf[gslot] = w * (h @ W2t^T + b2)  (bf16 streaming stores) ------
__global__ __launch_bounds__(512, 2) void k_gemm2(
    const unsigned short* __restrict__ hbuf, // [sum cnt][H] bf16
    const unsigned short* __restrict__ w2t,  // [E][D][H] bf16
    const float* __restrict__ b2,            // [E][D]
    const float* __restrict__ wts,
    const int* __restrict__ counts,
    unsigned short* __restrict__ ybuf)       // [sum cnt][D] bf16
{
  __shared__ unsigned short As[2][256 * 64];
  __shared__ unsigned short Bs[2][256 * 64];
  int cnts[E_], offsv[E_], rowt[E_];
  int s = 0, ntr = 0;
#pragma unroll
  for (int e = 0; e < E_; e++) {
    cnts[e] = counts[e];
    offsv[e] = s; s += cnts[e];
    rowt[e] = (cnts[e] + 255) >> 8; ntr += rowt[e];
  }
  const int NS = D_ / 256;                   // 8 col slabs
  int totalTiles = ntr * NS;
  int tid = threadIdx.x, lane = tid & 63, wid = tid >> 6;
  int wm = wid >> 2, wn = wid & 3;
  int cr = lane >> 3, slot = lane & 7;
  int sw = (slot ^ cr) << 3;
  int hi = lane >> 4, cl = lane & 15;
  int bswz = (blockIdx.x & 7) * (gridDim.x >> 3) + (blockIdx.x >> 3);

  for (int tile = bswz; tile < totalTiles; tile += gridDim.x) {
    int slab = tile / ntr;
    int rtg = tile - slab * ntr;
    int n0 = slab << 8;
    int e = 0, base = 0;
    while (e < E_ - 1 && rtg >= base + rowt[e]) { base += rowt[e]; e++; }
    int rt = rtg - base;
    int cnt = cnts[e];
    int r0 = rt << 8;
    int offe = offsv[e];

    const unsigned short* a_src[4];
    const unsigned short* b_src[4];
    const unsigned short* wbase = w2t + (size_t)e * D_ * H_;
#pragma unroll
    for (int i = 0; i < 4; i++) {
      int chunk = wid * 4 + i;
      int rr = r0 + chunk * 8 + cr;
      int rc = min(rr, cnt - 1);
      a_src[i] = hbuf + (size_t)(offe + rc) * H_ + sw;
      b_src[i] = wbase + (size_t)(n0 + chunk * 8 + cr) * H_ + sw;
    }
    f32x4_t acc[8][4];
#pragma unroll
    for (int m = 0; m < 8; m++)
#pragma unroll
      for (int n = 0; n < 4; n++) acc[m][n] = (f32x4_t){0.f, 0.f, 0.f, 0.f};

#pragma unroll
    for (int i = 0; i < 4; i++) {
      gld16(a_src[i], As[0] + (wid * 4 + i) * 512);
      gld16(b_src[i], Bs[0] + (wid * 4 + i) * 512);
    }
    __syncthreads();
    int cur = 0;
    for (int kt = 0; kt < H_ / 64; kt++) {
      if (kt + 1 < H_ / 64) {
        int ko = (kt + 1) * 64;
#pragma unroll
        for (int i = 0; i < 4; i++) {
          gld16(a_src[i] + ko, As[cur ^ 1] + (wid * 4 + i) * 512);
          gld16(b_src[i] + ko, Bs[cur ^ 1] + (wid * 4 + i) * 512);
        }
      }
#pragma unroll
      for (int kb = 0; kb < 2; kb++) {
        bf16x8_t af[8], bfr[4];
#pragma unroll
        for (int m = 0; m < 8; m++) {
          int row = wm * 128 + m * 16 + (lane & 15);
          int ss = (kb * 4 + (lane >> 4)) ^ (row & 7);
          af[m] = *(const bf16x8_t*)(As[cur] + row * 64 + ss * 8);
        }
#pragma unroll
        for (int n = 0; n < 4; n++) {
          int row = wn * 64 + n * 16 + (lane & 15);
          int ss = (kb * 4 + (lane >> 4)) ^ (row & 7);
          bfr[n] = *(const bf16x8_t*)(Bs[cur] + row * 64 + ss * 8);
        }
#pragma unroll
        for (int m = 0; m < 8; m++)
#pragma unroll
          for (int n = 0; n < 4; n++)
            acc[m][n] = __builtin_amdgcn_mfma_f32_16x16x32_bf16(af[m], bfr[n], acc[m][n], 0, 0, 0);
      }
      __syncthreads();
      cur ^= 1;
    }
    float bias[4];
#pragma unroll
    for (int n = 0; n < 4; n++)
      bias[n] = b2[e * D_ + n0 + wn * 64 + n * 16 + cl];
#pragma unroll
    for (int m = 0; m < 8; m++)
#pragma unroll
      for (int j = 0; j < 4; j++) {
        int sr = r0 + wm * 128 + m * 16 + hi * 4 + j;
        if (sr < cnt) {
          float w = wts[e * CAP + sr];
          unsigned short* yrow = ybuf + (size_t)(offe + sr) * D_;
#pragma unroll
          for (int n = 0; n < 4; n++) {
            int col = n0 + wn * 64 + n * 16 + cl;
            yrow[col] = f2bf(w * (acc[m][n][j] + bias[n]));
          }
        }
      }
  }
}

extern "C" void kernel_launch(void* const* d_in, const int* in_sizes, int n_in,
                              void* d_out, int out_size, void* d_ws, size_t ws_size,
                              hipStream_t stream) {
  const float* x  = (const float*)d_in[0];
  const float* W1 = (const float*)d_in[1];
  const float* b1 = (const float*)d_in[2];
  const float* W2 = (const float*)d_in[3];
  const float* b2 = (const float*)d_in[4];
  const float* Wr = (const float*)d_in[5];
  const float* br = (const float*)d_in[6];
  float* out = (float*)d_out;
  char* ws = (char*)d_ws;
  // workspace layout (~176.9 MiB total). ybuf ALIASES W1t (dead after gemm1).
  unsigned short* W1t  = (unsigned short*)(ws);                // 67108864 B [E][H][D] bf16
  unsigned short* ybuf = (unsigned short*)(ws);                // 67108864 B [16384][D] bf16
  unsigned short* W2t  = (unsigned short*)(ws + 67108864);     // 67108864 B [E][D][H] bf16
  unsigned short* xb   = (unsigned short*)(ws + 134217728);    // 16777216 B [B][D] bf16
  unsigned short* hb   = (unsigned short*)(ws + 150994944);    // 33554432 B [B*K][H] bf16
  int*   ids    = (int*)  (ws + 184549376);                    // 262144 B
  float* wts    = (float*)(ws + 184811520);                    // 262144 B
  int*   counts = (int*)  (ws + 185073664);                    // 64 B
  float* wrT    = (float*)(ws + 185073728);                    // 131072 B [E][D] f32
  int*   tops   = (int*)  (ws + 185204800);                    // 65536 B [B][4]
  float* topw   = (float*)(ws + 185270336);                    // 65536 B [B][4]
  int*   inv    = (int*)  (ws + 185335872);                    // 65536 B [B][4]

  k_transr<<<128, 256, 0, stream>>>(Wr, wrT);
  k_transw<<<dim3(32, 64, 16), 256, 0, stream>>>(W1, W1t, 2048, 1024);
  k_transw<<<dim3(64, 32, 16), 256, 0, stream>>>(W2, W2t, 1024, 2048);
  k_router<<<1024, 256, 0, stream>>>(x, wrT, br, xb, tops, topw);
  k_build<<<16, 256, 0, stream>>>(tops, topw, counts, ids, wts, inv);
  k_gemm1<<<256, 512, 0, stream>>>(xb, W1t, b1, ids, counts, hb);
  k_gemm2<<<256, 512, 0, stream>>>(hb, W2t, b2, wts, counts, ybuf);
  k_gather<<<4096, 256, 0, stream>>>(x, ybuf, inv, out);
}

// Round 11
// 442.243 us; speedup vs baseline: 1.1731x; 1.1329x over previous
//
#include <hip/hip_runtime.h>
#include <math.h>

#define D_   2048
#define E_   16
#define H_   1024
#define KSEL 4
#define B_   4096
#define CAP  4096

typedef short bf16x8_t __attribute__((ext_vector_type(8)));
typedef float f32x4_t  __attribute__((ext_vector_type(4)));

__device__ __forceinline__ unsigned short f2bf(float f) {
  unsigned u = __float_as_uint(f);
  u += 0x7FFFu + ((u >> 16) & 1u);   // RNE
  return (unsigned short)(u >> 16);
}

__device__ __forceinline__ float bf2f(unsigned short h) {
  unsigned u = (unsigned)h << 16;
  return __uint_as_float(u);
}

__device__ __forceinline__ void gld16(const void* g, void* l) {
  __builtin_amdgcn_global_load_lds(
      (const __attribute__((address_space(1))) unsigned int*)g,
      (__attribute__((address_space(3))) unsigned int*)l, 16, 0, 0);
}

// ---------------- W [E][R][C] f32 -> Wt [E][C][R] bf16 ----------------
__global__ void k_transw(const float* __restrict__ in, unsigned short* __restrict__ out,
                         int R, int C) {
  __shared__ float tile[32][33];
  size_t ebase = (size_t)blockIdx.z * R * C;
  in += ebase; out += ebase;
  int c0 = blockIdx.x * 32, r0 = blockIdx.y * 32;
  int tx = threadIdx.x & 31, ty = threadIdx.x >> 5;
#pragma unroll
  for (int i = ty; i < 32; i += 8)
    tile[i][tx] = in[(size_t)(r0 + i) * C + c0 + tx];
  __syncthreads();
  // write ushort2 pairs along R (output-contiguous)
#pragma unroll
  for (int w = threadIdx.x; w < 32 * 16; w += 256) {
    int i = w >> 4, rp = w & 15;
    ushort2 v;
    v.x = f2bf(tile[2 * rp][i]);
    v.y = f2bf(tile[2 * rp + 1][i]);
    *(ushort2*)(out + (size_t)(c0 + i) * R + r0 + 2 * rp) = v;
  }
}

// ---------------- Wr [D][E] f32 -> WrT [E][D] f32 (128 KB, one-shot) ----------
__global__ void k_transr(const float* __restrict__ in, float* __restrict__ out) {
  int i = blockIdx.x * 256 + threadIdx.x;   // coalesced read over D*E
  int d = i >> 4, e = i & 15;
  out[e * D_ + d] = in[i];                  // scattered 16-stream write; L2 absorbs
}

// ------- fused: router (logits/top4/softmax -> tops/topw) + x->bf16 store ------
__global__ __launch_bounds__(256) void k_router(
    const float* __restrict__ x, const float* __restrict__ wrT, const float* __restrict__ br,
    unsigned short* __restrict__ xb, int* __restrict__ tops, float* __restrict__ topw) {
  int wid = threadIdx.x >> 6, lane = threadIdx.x & 63;
  int t = blockIdx.x * 4 + wid;
  float acc[E_];
#pragma unroll
  for (int e = 0; e < E_; e++) acc[e] = 0.f;
  const float4* xr = (const float4*)(x + (size_t)t * D_);
  ushort4* xbw = (ushort4*)(xb + (size_t)t * D_);
#pragma unroll
  for (int j = 0; j < D_ / 256; j++) {
    float4 xv = xr[j * 64 + lane];
    ushort4 o;
    o.x = f2bf(xv.x); o.y = f2bf(xv.y); o.z = f2bf(xv.z); o.w = f2bf(xv.w);
    xbw[j * 64 + lane] = o;
#pragma unroll
    for (int e = 0; e < E_; e++) {
      float4 wv = ((const float4*)(wrT + (size_t)e * D_))[j * 64 + lane];
      acc[e] += xv.x * wv.x + xv.y * wv.y + xv.z * wv.z + xv.w * wv.w;
    }
  }
#pragma unroll
  for (int e = 0; e < E_; e++) {
    float v = acc[e];
    for (int m = 32; m >= 1; m >>= 1) v += __shfl_xor(v, m);
    acc[e] = v;
  }
  if (lane == 0) {
    float lg[E_];
#pragma unroll
    for (int e = 0; e < E_; e++) lg[e] = acc[e] + br[e];
    unsigned used = 0; int sel[KSEL]; float sv[KSEL];
    for (int k = 0; k < KSEL; k++) {
      float best = -1e30f; int bi = 0;
      for (int e = 0; e < E_; e++)
        if (!((used >> e) & 1u) && lg[e] > best) { best = lg[e]; bi = e; }
      used |= 1u << bi; sel[k] = bi; sv[k] = best;
    }
    float mx = sv[0], s = 0.f, w[KSEL];
    for (int k = 0; k < KSEL; k++) { w[k] = expf(sv[k] - mx); s += w[k]; }
    float inv = 1.f / s;
    int4 ti; float4 tw;
    ti.x = sel[0]; ti.y = sel[1]; ti.z = sel[2]; ti.w = sel[3];
    tw.x = w[0] * inv; tw.y = w[1] * inv; tw.z = w[2] * inv; tw.w = w[3] * inv;
    ((int4*)tops)[t] = ti;
    ((float4*)topw)[t] = tw;
  }
}

// ------- build per-expert token lists + inverse map (deterministic, no atomics)
__global__ __launch_bounds__(256) void k_build(
    const int* __restrict__ tops, const float* __restrict__ topw,
    int* __restrict__ counts, int* __restrict__ ids, float* __restrict__ wts,
    int* __restrict__ inv) {
  int e = blockIdx.x;
  int tid = threadIdx.x, lane = tid & 63, wid = tid >> 6;
  __shared__ int wsum[4];
  __shared__ int red[4];
  int base = 0;
  int pre = 0;                               // picks with expert < e (per thread)
  for (int c = 0; c < B_; c += 256) {
    int t = c + tid;
    int4 tk = ((const int4*)tops)[t];
    pre += (tk.x < e) + (tk.y < e) + (tk.z < e) + (tk.w < e);
    int k = -1;
    if (tk.x == e) k = 0; else if (tk.y == e) k = 1;
    else if (tk.z == e) k = 2; else if (tk.w == e) k = 3;
    unsigned long long mask = __ballot(k >= 0);
    int myoff = __popcll(mask & ((1ull << lane) - 1ull));
    if (lane == 0) wsum[wid] = __popcll(mask);
    __syncthreads();
    int woff = 0;
#pragma unroll
    for (int i = 0; i < 4; i++) if (i < wid) woff += wsum[i];
    int ctotal = wsum[0] + wsum[1] + wsum[2] + wsum[3];
    if (k >= 0) {
      int slot = base + woff + myoff;
      ids[e * CAP + slot] = t;
      wts[e * CAP + slot] = topw[t * 4 + k];
    }
    base += ctotal;
    __syncthreads();
  }
  if (tid == 0) counts[e] = base;
  for (int m = 32; m >= 1; m >>= 1) pre += __shfl_xor(pre, m);
  if (lane == 0) red[wid] = pre;
  __syncthreads();
  int offe = red[0] + red[1] + red[2] + red[3];
  for (int s = tid; s < base; s += 256) {
    int t = ids[e * CAP + s];
    int4 tk = ((const int4*)tops)[t];
    int k = (tk.x == e) ? 0 : (tk.y == e) ? 1 : (tk.z == e) ? 2 : 3;
    inv[t * 4 + k] = offe + s;
  }
}

// ---------------- gather: out[t] = x[t] + sum_k ybuf[inv[t][k]] ----------------
__global__ __launch_bounds__(256) void k_gather(
    const float* __restrict__ x, const unsigned short* __restrict__ ybuf,
    const int* __restrict__ inv, float* __restrict__ out) {
  int t = blockIdx.x;
  int4 iv = ((const int4*)inv)[t];
  const ushort4* y0 = (const ushort4*)(ybuf + (size_t)iv.x * D_);
  const ushort4* y1 = (const ushort4*)(ybuf + (size_t)iv.y * D_);
  const ushort4* y2 = (const ushort4*)(ybuf + (size_t)iv.z * D_);
  const ushort4* y3 = (const ushort4*)(ybuf + (size_t)iv.w * D_);
  const float4* xr = (const float4*)(x + (size_t)t * D_);
  float4* orow = (float4*)(out + (size_t)t * D_);
#pragma unroll
  for (int i = threadIdx.x; i < D_ / 4; i += 256) {
    float4 v = xr[i];
    ushort4 a = y0[i], b = y1[i], c = y2[i], d = y3[i];
    v.x += bf2f(a.x) + bf2f(b.x) + bf2f(c.x) + bf2f(d.x);
    v.y += bf2f(a.y) + bf2f(b.y) + bf2f(c.y) + bf2f(d.y);
    v.z += bf2f(a.z) + bf2f(b.z) + bf2f(c.z) + bf2f(d.z);
    v.w += bf2f(a.w) + bf2f(b.w) + bf2f(c.w) + bf2f(d.w);
    orow[i] = v;
  }
}

// ====== GEMM geometry: BM=128 x BN=128, BK=64, 4 waves (256 thr) ======
// Co-residency bet: 32KB LDS single-buffer + acc[4][4] (64 AGPR) + bounds
// (256,3) -> 3 blocks/CU (12 waves). R8's serial loop (stage->sync->compute->
// sync) unchanged: co-resident blocks hide each other's vmcnt(0) drains.
// wave (wr,wc) of 2x2 owns 64x64. XOR-swizzled staging. Slab-outer worklist.

// ---------------- GEMM1: h = relu(X[ids] @ W1t^T + b1), bf16 out ----------------
__global__ __launch_bounds__(256, 3) void k_gemm1(
    const unsigned short* __restrict__ xb,   // [B][D] bf16
    const unsigned short* __restrict__ w1t,  // [E][H][D] bf16
    const float* __restrict__ b1,            // [E][H]
    const int* __restrict__ ids, const int* __restrict__ counts,
    unsigned short* __restrict__ hbuf)       // [sum cnt][H] bf16
{
  __shared__ unsigned short As[128 * 64];
  __shared__ unsigned short Bs[128 * 64];
  int cnts[E_], offsv[E_], rowt[E_];
  int s = 0, ntr = 0;
#pragma unroll
  for (int e = 0; e < E_; e++) {
    cnts[e] = counts[e];
    offsv[e] = s; s += cnts[e];
    rowt[e] = (cnts[e] + 127) >> 7; ntr += rowt[e];
  }
  const int NS = H_ / 128;                   // 8 col slabs
  int totalTiles = ntr * NS;
  int tid = threadIdx.x, lane = tid & 63, wid = tid >> 6;
  int wr = wid >> 1, wc = wid & 1;
  int cr = lane >> 3, slot = lane & 7;
  int sw = (slot ^ cr) << 3;                 // swizzled k-chunk (elements)
  int hi = lane >> 4, cl = lane & 15;
  int bswz = (blockIdx.x & 7) * (gridDim.x >> 3) + (blockIdx.x >> 3);

  for (int tile = bswz; tile < totalTiles; tile += gridDim.x) {
    int slab = tile / ntr;                   // slab-outer, row-inner
    int rtg = tile - slab * ntr;
    int n0 = slab << 7;
    int e = 0, base = 0;
    while (e < E_ - 1 && rtg >= base + rowt[e]) { base += rowt[e]; e++; }
    int rt = rtg - base;
    int cnt = cnts[e];
    int r0 = rt << 7;

    const unsigned short* a_src[4];
    const unsigned short* b_src[4];
    const unsigned short* wbase = w1t + (size_t)e * H_ * D_;
#pragma unroll
    for (int i = 0; i < 4; i++) {
      int chunk = wid * 4 + i;               // 16 chunks x 8 rows = 128
      int rr = r0 + chunk * 8 + cr;
      int rc = min(rr, cnt - 1);
      int tok = ids[e * CAP + rc];
      a_src[i] = xb + (size_t)tok * D_ + sw;
      b_src[i] = wbase + (size_t)(n0 + chunk * 8 + cr) * D_ + sw;
    }
    f32x4_t acc[4][4];
#pragma unroll
    for (int m = 0; m < 4; m++)
#pragma unroll
      for (int n = 0; n < 4; n++) acc[m][n] = (f32x4_t){0.f, 0.f, 0.f, 0.f};

    for (int kt = 0; kt < D_; kt += 64) {
#pragma unroll
      for (int i = 0; i < 4; i++) {
        gld16(a_src[i] + kt, As + (wid * 4 + i) * 512);
        gld16(b_src[i] + kt, Bs + (wid * 4 + i) * 512);
      }
      __syncthreads();
#pragma unroll
      for (int kb = 0; kb < 2; kb++) {
        bf16x8_t af[4], bfr[4];
#pragma unroll
        for (int m = 0; m < 4; m++) {
          int row = wr * 64 + m * 16 + (lane & 15);
          int ss = (kb * 4 + (lane >> 4)) ^ (row & 7);
          af[m] = *(const bf16x8_t*)(As + row * 64 + ss * 8);
        }
#pragma unroll
        for (int n = 0; n < 4; n++) {
          int row = wc * 64 + n * 16 + (lane & 15);
          int ss = (kb * 4 + (lane >> 4)) ^ (row & 7);
          bfr[n] = *(const bf16x8_t*)(Bs + row * 64 + ss * 8);
        }
#pragma unroll
        for (int m = 0; m < 4; m++)
#pragma unroll
          for (int n = 0; n < 4; n++)
            acc[m][n] = __builtin_amdgcn_mfma_f32_16x16x32_bf16(af[m], bfr[n], acc[m][n], 0, 0, 0);
      }
      __syncthreads();
    }
    int offe = offsv[e];
    float bias[4];
#pragma unroll
    for (int n = 0; n < 4; n++)
      bias[n] = b1[e * H_ + n0 + wc * 64 + n * 16 + cl];
#pragma unroll
    for (int m = 0; m < 4; m++)
#pragma unroll
      for (int j = 0; j < 4; j++) {
        int sr = r0 + wr * 64 + m * 16 + hi * 4 + j;
        if (sr < cnt) {
          size_t rowb = (size_t)(offe + sr) * H_;
#pragma unroll
          for (int n = 0; n < 4; n++) {
            int col = n0 + wc * 64 + n * 16 + cl;
            float v = acc[m][n][j] + bias[n];
            v = v > 0.f ? v : 0.f;
            hbuf[rowb + col] = f2bf(v);
          }
        }
      }
  }
}

// ------ GEMM2: ybuf[gslot] = w * (h @ W2t^T + b2)  (bf16 streaming stores) ------
__global__ __launch_bounds__(256, 3) void k_gemm2(
    const unsigned short* __restrict__ hbuf, // [sum cnt][H] bf16
    const unsigned short* __restrict__ w2t,  // [E][D][H] bf16
    const float* __restrict__ b2,            // [E][D]
    const float* __restrict__ wts,
    const int* __restrict__ counts,
    unsigned short* __restrict__ ybuf)       // [sum cnt][D] bf16
{
  __shared__ unsigned short As[128 * 64];
  __shared__ unsigned short Bs[128 * 64];
  int cnts[E_], offsv[E_], rowt[E_];
  int s = 0, ntr = 0;
#pragma unroll
  for (int e = 0; e < E_; e++) {
    cnts[e] = counts[e];
    offsv[e] = s; s += cnts[e];
    rowt[e] = (cnts[e] + 127) >> 7; ntr += rowt[e];
  }
  const int NS = D_ / 128;                   // 16 col slabs
  int totalTiles = ntr * NS;
  int tid = threadIdx.x, lane = tid & 63, wid = tid >> 6;
  int wr = wid >> 1, wc = wid & 1;
  int cr = lane >> 3, slot = lane & 7;
  int sw = (slot ^ cr) << 3;
  int hi = lane >> 4, cl = lane & 15;
  int bswz = (blockIdx.x & 7) * (gridDim.x >> 3) + (blockIdx.x >> 3);

  for (int tile = bswz; tile < totalTiles; tile += gridDim.x) {
    int slab = tile / ntr;
    int rtg = tile - slab * ntr;
    int n0 = slab << 7;
    int e = 0, base = 0;
    while (e < E_ - 1 && rtg >= base + rowt[e]) { base += rowt[e]; e++; }
    int rt = rtg - base;
    int cnt = cnts[e];
    int r0 = rt << 7;
    int offe = offsv[e];

    const unsigned short* a_src[4];
    const unsigned short* b_src[4];
    const unsigned short* wbase = w2t + (size_t)e * D_ * H_;
#pragma unroll
    for (int i = 0; i < 4; i++) {
      int chunk = wid * 4 + i;
      int rr = r0 + chunk * 8 + cr;
      int rc = min(rr, cnt - 1);
      a_src[i] = hbuf + (size_t)(offe + rc) * H_ + sw;
      b_src[i] = wbase + (size_t)(n0 + chunk * 8 + cr) * H_ + sw;
    }
    f32x4_t acc[4][4];
#pragma unroll
    for (int m = 0; m < 4; m++)
#pragma unroll
      for (int n = 0; n < 4; n++) acc[m][n] = (f32x4_t){0.f, 0.f, 0.f, 0.f};

    for (int kt = 0; kt < H_; kt += 64) {
#pragma unroll
      for (int i = 0; i < 4; i++) {
        gld16(a_src[i] + kt, As + (wid * 4 + i) * 512);
        gld16(b_src[i] + kt, Bs + (wid * 4 + i) * 512);
      }
      __syncthreads();
#pragma unroll
      for (int kb = 0; kb < 2; kb++) {
        bf16x8_t af[4], bfr[4];
#pragma unroll
        for (int m = 0; m < 4; m++) {
          int row = wr * 64 + m * 16 + (lane & 15);
          int ss = (kb * 4 + (lane >> 4)) ^ (row & 7);
          af[m] = *(const bf16x8_t*)(As + row * 64 + ss * 8);
        }
#pragma unroll
        for (int n = 0; n < 4; n++) {
          int row = wc * 64 + n * 16 + (lane & 15);
          int ss = (kb * 4 + (lane >> 4)) ^ (row & 7);
          bfr[n] = *(const bf16x8_t*)(Bs + row * 64 + ss * 8);
        }
#pragma unroll
        for (int m = 0; m < 4; m++)
#pragma unroll
          for (int n = 0; n < 4; n++)
            acc[m][n] = __builtin_amdgcn_mfma_f32_16x16x32_bf16(af[m], bfr[n], acc[m][n], 0, 0, 0);
      }
      __syncthreads();
    }
    float bias[4];
#pragma unroll
    for (int n = 0; n < 4; n++)
      bias[n] = b2[e * D_ + n0 + wc * 64 + n * 16 + cl];
#pragma unroll
    for (int m = 0; m < 4; m++)
#pragma unroll
      for (int j = 0; j < 4; j++) {
        int sr = r0 + wr * 64 + m * 16 + hi * 4 + j;
        if (sr < cnt) {
          float w = wts[e * CAP + sr];
          unsigned short* yrow = ybuf + (size_t)(offe + sr) * D_;
#pragma unroll
          for (int n = 0; n < 4; n++) {
            int col = n0 + wc * 64 + n * 16 + cl;
            yrow[col] = f2bf(w * (acc[m][n][j] + bias[n]));
          }
        }
      }
  }
}

extern "C" void kernel_launch(void* const* d_in, const int* in_sizes, int n_in,
                              void* d_out, int out_size, void* d_ws, size_t ws_size,
                              hipStream_t stream) {
  const float* x  = (const float*)d_in[0];
  const float* W1 = (const float*)d_in[1];
  const float* b1 = (const float*)d_in[2];
  const float* W2 = (const float*)d_in[3];
  const float* b2 = (const float*)d_in[4];
  const float* Wr = (const float*)d_in[5];
  const float* br = (const float*)d_in[6];
  float* out = (float*)d_out;
  char* ws = (char*)d_ws;
  // workspace layout (~176.9 MiB total). ybuf ALIASES W1t (dead after gemm1).
  unsigned short* W1t  = (unsigned short*)(ws);                // 67108864 B [E][H][D] bf16
  unsigned short* ybuf = (unsigned short*)(ws);                // 67108864 B [16384][D] bf16
  unsigned short* W2t  = (unsigned short*)(ws + 67108864);     // 67108864 B [E][D][H] bf16
  unsigned short* xb   = (unsigned short*)(ws + 134217728);    // 16777216 B [B][D] bf16
  unsigned short* hb   = (unsigned short*)(ws + 150994944);    // 33554432 B [B*K][H] bf16
  int*   ids    = (int*)  (ws + 184549376);                    // 262144 B
  float* wts    = (float*)(ws + 184811520);                    // 262144 B
  int*   counts = (int*)  (ws + 185073664);                    // 64 B
  float* wrT    = (float*)(ws + 185073728);                    // 131072 B [E][D] f32
  int*   tops   = (int*)  (ws + 185204800);                    // 65536 B [B][4]
  float* topw   = (float*)(ws + 185270336);                    // 65536 B [B][4]
  int*   inv    = (int*)  (ws + 185335872);                    // 65536 B [B][4]

  k_transr<<<128, 256, 0, stream>>>(Wr, wrT);
  k_transw<<<dim3(32, 64, 16), 256, 0, stream>>>(W1, W1t, 2048, 1024);
  k_transw<<<dim3(64, 32, 16), 256, 0, stream>>>(W2, W2t, 1024, 2048);
  k_router<<<1024, 256, 0, stream>>>(x, wrT, br, xb, tops, topw);
  k_build<<<16, 256, 0, stream>>>(tops, topw, counts, ids, wts, inv);
  k_gemm1<<<768, 256, 0, stream>>>(xb, W1t, b1, ids, counts, hb);
  k_gemm2<<<768, 256, 0, stream>>>(hb, W2t, b2, wts, counts, ybuf);
  k_gather<<<4096, 256, 0, stream>>>(x, ybuf, inv, out);
}